// Round 11
// baseline (241.516 us; speedup 1.0000x reference)
//
#include <hip/hip_runtime.h>

typedef __bf16 bf16;
typedef float f32x4 __attribute__((ext_vector_type(4)));
typedef bf16 bf16x8v __attribute__((ext_vector_type(8)));
typedef bf16 bf16x4v __attribute__((ext_vector_type(4)));

#define MFMA_BF16(a, b, c) __builtin_amdgcn_mfma_f32_16x16x32_bf16((a), (b), (c), 0, 0, 0)

// async global->LDS, 16B per lane (dest = wave-uniform base + lane*16)
__device__ __forceinline__ void async16(const bf16* g, bf16* l) {
  __builtin_amdgcn_global_load_lds(
      (const __attribute__((address_space(1))) void*)g,
      (__attribute__((address_space(3))) void*)l, 16, 0, 0);
}

// ---------------------------------------------------------------------------
// Fused prep: f32->bf16 convert of x  +  two transpose+convert of weights.
// ---------------------------------------------------------------------------
__global__ __launch_bounds__(256) void prep_kernel(
    const float* __restrict__ x, bf16* __restrict__ xb,
    const float* __restrict__ w_attn, bf16* __restrict__ wt_attn,
    const float* __restrict__ w_proj, bf16* __restrict__ wt_proj) {
  __shared__ float tile[32][33];
  const int b = blockIdx.x;
  if (b < 3072) {
    int i = b * 256 + threadIdx.x;
    const float4* p = (const float4*)x + (size_t)i * 2;
    float4 a = p[0], c = p[1];
    bf16x8v o;
    o[0] = (bf16)a.x; o[1] = (bf16)a.y; o[2] = (bf16)a.z; o[3] = (bf16)a.w;
    o[4] = (bf16)c.x; o[5] = (bf16)c.y; o[6] = (bf16)c.z; o[7] = (bf16)c.w;
    ((bf16x8v*)xb)[i] = o;
    return;
  }
  const float* in;
  bf16* out;
  int Ccols, bidx;
  if (b < 4800) {
    in = w_attn; out = wt_attn; Ccols = 2304; bidx = b - 3072;
  } else {
    in = w_proj; out = wt_proj; Ccols = 768; bidx = b - 4800;
  }
  const int R = 768;
  const int gx = Ccols / 32;
  const int c0 = (bidx % gx) * 32, r0 = (bidx / gx) * 32;
  const int tx = threadIdx.x & 31;
  const int ty = threadIdx.x >> 5;
#pragma unroll
  for (int i = 0; i < 4; ++i) {
    int r = ty + i * 8;
    tile[r][tx] = in[(size_t)(r0 + r) * Ccols + c0 + tx];
  }
  __syncthreads();
#pragma unroll
  for (int i = 0; i < 4; ++i) {
    int c = ty + i * 8;
    out[(size_t)(c0 + c) * R + r0 + tx] = (bf16)tile[tx][c];
  }
}

// ---------------------------------------------------------------------------
// Tiled bf16 transpose: out[z][c][r] = in[z][r][c].  R,C mult of 32.
// ---------------------------------------------------------------------------
__global__ __launch_bounds__(256) void transpose_bf16_kernel(
    const bf16* __restrict__ in, bf16* __restrict__ out, int R, int Ccols) {
  __shared__ bf16 tile[32][33];
  const bf16* inp = in + (size_t)blockIdx.z * R * Ccols;
  bf16* outp = out + (size_t)blockIdx.z * R * Ccols;
  int c0 = blockIdx.x * 32, r0 = blockIdx.y * 32;
  int tx = threadIdx.x & 31;
  int ty = threadIdx.x >> 5;
#pragma unroll
  for (int i = 0; i < 4; ++i) {
    int r = ty + i * 8;
    tile[r][tx] = inp[(size_t)(r0 + r) * Ccols + c0 + tx];
  }
  __syncthreads();
#pragma unroll
  for (int i = 0; i < 4; ++i) {
    int c = ty + i * 8;
    outp[(size_t)(c0 + c) * R + r0 + tx] = tile[tx][c];
  }
}

// ---------------------------------------------------------------------------
// GEMM: out[M][N] = A[M][768] * Bt[N][768]^T + bias[N]   (A,Bt bf16; bias f32)
// MODE 0: store FLOAT to outf.  MODE 1: scatter bf16 into q/k/v [b,h,t,d].
// BM x 128 tile (BM=128 or 64), BK=64, 4 waves, async global_load_lds
// staging with XOR swizzle (conflict-free b128 frag reads).  XCD-affine
// 1-D grid (T1): m-tiles contiguous per XCD, n slowest.
// BM=64 for the small N=768 GEMM: 768 blocks = 3/CU (the 128-tile grid of
// 384 = 1.5/CU serialized 2 blocks on half the CUs while half idled).
// ---------------------------------------------------------------------------
template <int MODE, int BM>
__global__ __launch_bounds__(256) void gemm_kernel(
    const bf16* __restrict__ A, const bf16* __restrict__ Bt,
    const float* __restrict__ bias, int N, float* __restrict__ outf,
    bf16* __restrict__ qo, bf16* __restrict__ ko, bf16* __restrict__ vo) {
  constexpr int Kdim = 768;
  constexpr int MI = BM / 32;  // per-wave m-fragments
  __shared__ __align__(16) bf16 As[BM][64];
  __shared__ __align__(16) bf16 Bs[128][64];
  const int tid = threadIdx.x;
  const int lane = tid & 63;
  const int wave = tid >> 6;
  const int wm = (wave >> 1) * (BM / 2), wn = (wave & 1) * 64;
  const int id = blockIdx.x;
  const int xcd = id & 7, j = id >> 3;
  int m0, n0;
  if (BM == 128) {
    m0 = (xcd * 8 + (j & 7)) * 128;   // 8 m-tiles per XCD
    n0 = (j >> 3) * 128;
  } else {
    m0 = (xcd * 16 + (j & 15)) * 64;  // 16 m-tiles per XCD
    n0 = (j >> 4) * 128;
  }
  const int l15 = lane & 15, q4 = lane >> 4;
  const int swz = l15 & 7;

  f32x4 acc[MI][4] = {};

  const int gr = lane >> 3;        // row within 8-row group
  const int sj = (lane & 7) ^ gr;  // global source chunk (XOR swizzle)

  for (int k0 = 0; k0 < Kdim; k0 += 64) {
#pragma unroll
    for (int c = 0; c < BM / 32; ++c) {
      const int r0 = wave * (BM / 4) + c * 8;
      async16(A + (size_t)(m0 + r0 + gr) * Kdim + k0 + sj * 8, &As[r0][0]);
    }
#pragma unroll
    for (int c = 0; c < 4; ++c) {
      const int r0 = wave * 32 + c * 8;
      async16(Bt + (size_t)(n0 + r0 + gr) * Kdim + k0 + sj * 8, &Bs[r0][0]);
    }
    __syncthreads();
#pragma unroll
    for (int ks = 0; ks < 2; ++ks) {
      bf16x8v af[MI], bfg[4];
#pragma unroll
      for (int i = 0; i < MI; ++i)
        af[i] =
            *(const bf16x8v*)&As[wm + i * 16 + l15][((ks * 4 + q4) ^ swz) * 8];
#pragma unroll
      for (int i = 0; i < 4; ++i)
        bfg[i] =
            *(const bf16x8v*)&Bs[wn + i * 16 + l15][((ks * 4 + q4) ^ swz) * 8];
#pragma unroll
      for (int mi = 0; mi < MI; ++mi)
#pragma unroll
        for (int ni = 0; ni < 4; ++ni)
          acc[mi][ni] = MFMA_BF16(af[mi], bfg[ni], acc[mi][ni]);
    }
    __syncthreads();
  }

#pragma unroll
  for (int mi = 0; mi < MI; ++mi) {
#pragma unroll
    for (int ni = 0; ni < 4; ++ni) {
      int col = n0 + wn + ni * 16 + l15;
      float bv = bias[col];
#pragma unroll
      for (int r = 0; r < 4; ++r) {
        int row = m0 + wm + mi * 16 + q4 * 4 + r;
        float val = acc[mi][ni][r] + bv;
        if (MODE == 0) {
          outf[(size_t)row * N + col] = val;
        } else {
          int sel = col / 768;
          int cc = col - sel * 768;
          int h = cc >> 6, d = cc & 63;
          int b = row >> 12, t = row & 4095;
          bf16* dst = sel == 0 ? qo : (sel == 1 ? ko : vo);
          dst[((size_t)(b * 12 + h) * 4096 + t) * 64 + d] = (bf16)val;
        }
      }
    }
  }
}

// ---------------------------------------------------------------------------
// Flash attention — R6 body verbatim; NEW id->(bh,p) map: constant-triplet
// p-sum WITH XCD affinity (the R3 idea done right).
//
//   r=id&255 (CU slot), s=id>>8 (residency round), m=r>>3, rho=r&7,
//   b=(m+s)%3, bh=rho+8b, p=pi_b(m)
//   pi_0=m; pi_1= m<16?30-2m:63-2m; pi_2=(m+16)&31  (pointwise sum 46/47)
//
// Properties: (1) every block of head bh has id = rho (mod 8) -> one XCD
// per head, 3 heads/XCD — same L2 traffic as the proven bh=id%24 map
// (guard: FETCH must stay ~18.5MB; R3's map broke this -> 102MB).
// (2) CU slot r's three blocks share m -> duration sum 64*3-(46|47) =
// 145/146 iters for EVERY CU (old map: 128..160, 20% spread).
// (3) bijective: m = pi_b^-1(p), s = (b-m) mod 3.
// ---------------------------------------------------------------------------
__global__ __launch_bounds__(512, 6) void attn_kernel(
    const bf16* __restrict__ q, const bf16* __restrict__ k,
    const bf16* __restrict__ vt, bf16* __restrict__ y) {
  __shared__ __align__(16) bf16 Kb[2][64][64];  // [key][d], swizzled
  __shared__ __align__(16) bf16 Vb[2][64][64];  // [d][key], swizzled
  __shared__ __align__(16) bf16 Ps[8][16][64];  // per-wave P, swizzled
  const int tid = threadIdx.x;
  const int lane = tid & 63, wave = tid >> 6;  // wave 0..7
  const int l15 = lane & 15, q4 = lane >> 4;
  const int swz = l15 & 7;
  const int id = blockIdx.x;
  const int r_ = id & 255, s_ = id >> 8;
  const int m_ = r_ >> 3, rho = r_ & 7;
  const int b_ = (m_ + s_) % 3;
  const int bh = rho + 8 * b_;
  const int p = (b_ == 0) ? m_
              : (b_ == 1) ? ((m_ < 16) ? 30 - 2 * m_ : 63 - 2 * m_)
                          : ((m_ + 16) & 31);
  // wave role: one 16-row strip.  waves 0-3: big tile 63-p; 4-7: small tile p
  const int rs = (wave < 4) ? ((63 - p) * 64 + wave * 16)
                            : (p * 64 + (wave - 4) * 16);
  const int hb = bh % 12, bb = bh / 12;

  // staging geometry: one async16 wave-call covers 8 rows x 8 chunks (1 KB);
  // each of 8 waves stages one 8-row group of K and of V.
  const int gr = lane >> 3;        // row within 8-row group
  const int sj = (lane & 7) ^ gr;  // global source chunk (XOR swizzle)
  const bf16* kgbase = k + (size_t)bh * 4096 * 64;
  const bf16* vgbase = vt + (size_t)bh * 64 * 4096;

  bf16x8v ones;
#pragma unroll
  for (int j = 0; j < 8; ++j) ones[j] = (bf16)1.0f;

  // Q fragments for this wave's strip, pre-scaled by log2(e)/sqrt(64)
  bf16x8v qf[2];
  {
    const bf16* qrow = q + ((size_t)bh * 4096 + rs + l15) * 64 + q4 * 8;
#pragma unroll
    for (int ks = 0; ks < 2; ++ks) {
      bf16x8v t8 = *(const bf16x8v*)(qrow + ks * 32);
#pragma unroll
      for (int j = 0; j < 8; ++j) t8[j] = (bf16)((float)t8[j] * 0.18033688f);
      qf[ks] = t8;
    }
  }

  f32x4 o[4] = {};
  f32x4 ol = {};

  auto stage = [&](int kt, int buf) {
    const int t0k = kt * 64;
    async16(kgbase + (size_t)(t0k + wave * 8 + gr) * 64 + sj * 8,
            &Kb[buf][wave * 8][0]);
    async16(vgbase + (size_t)(wave * 8 + gr) * 4096 + t0k + sj * 8,
            &Vb[buf][wave * 8][0]);
  };

  // p = exp2(s - 28.854); full (no mask) variant
  auto sm_full = [&](f32x4 (&s)[4]) {
#pragma unroll
    for (int ni = 0; ni < 4; ++ni)
#pragma unroll
      for (int r = 0; r < 4; ++r)
        s[ni][r] = __builtin_amdgcn_exp2f(s[ni][r] - 28.8539008f);
  };
  // masked variant: local key (ni*16+q4*4+r) valid iff <= lim
  auto sm_mask = [&](f32x4 (&s)[4], int lim) {
#pragma unroll
    for (int ni = 0; ni < 4; ++ni)
#pragma unroll
      for (int r = 0; r < 4; ++r)
        s[ni][r] = (ni * 16 + q4 * 4 + r <= lim)
                       ? __builtin_amdgcn_exp2f(s[ni][r] - 28.8539008f)
                       : 0.0f;
  };
  // P row write: lane (q4,l15) owns keys ni*16 + q4*4 + {0..3} of q-row l15.
  auto pwrite = [&](const f32x4 (&s)[4]) {
#pragma unroll
    for (int ni = 0; ni < 4; ++ni) {
      bf16x4v pv4;
#pragma unroll
      for (int e = 0; e < 4; ++e) pv4[e] = (bf16)s[ni][e];
      const int jb = ni * 2 + (q4 >> 1);
      *(bf16x4v*)&Ps[wave][l15][((jb ^ (l15 & 7)) * 8) + (q4 & 1) * 4] = pv4;
    }
  };

  const int ktmax = 64 - p;  // tiles needed by the big tile
  stage(0, 0);

  for (int kt = 0; kt < ktmax; ++kt) {
    const int buf = kt & 1;
    __syncthreads();  // drains vmcnt: tile kt resident; buf^1 free
    if (kt + 1 < ktmax) stage(kt + 1, buf ^ 1);
    const int t0 = kt * 64;

    if (t0 <= rs + 15) {  // wave-uniform: this strip still has work
      // S^T = K Q^T (exp2 domain)
      // Lane (q4,l15): s[ni][r] = S[qrow = rs + l15][key = t0+ni*16+q4*4+r]
      f32x4 s[4] = {};
      __builtin_amdgcn_s_setprio(1);
#pragma unroll
      for (int ni = 0; ni < 4; ++ni) {
#pragma unroll
        for (int ks = 0; ks < 2; ++ks) {
          bf16x8v kf = *(const bf16x8v*)&Kb[buf][ni * 16 + l15]
                                           [((ks * 4 + q4) ^ swz) * 8];
          s[ni] = MFMA_BF16(kf, qf[ks], s[ni]);
        }
      }
      __builtin_amdgcn_s_setprio(0);

      // softmax + P write (masked only near the diagonal)
      if (t0 + 63 <= rs) sm_full(s); else sm_mask(s, rs + l15 - t0);
      pwrite(s);

      // PV A-frag: proven swizzled b128 read path (row = q_row = l15)
      bf16x8v pf[2];
#pragma unroll
      for (int ks = 0; ks < 2; ++ks)
        pf[ks] = *(const bf16x8v*)&Ps[wave][l15][((ks * 4 + q4) ^ swz) * 8];

      // O += P V ; rowsum l += P * ones
      __builtin_amdgcn_s_setprio(1);
#pragma unroll
      for (int d4 = 0; d4 < 4; ++d4) {
#pragma unroll
        for (int ks = 0; ks < 2; ++ks) {
          bf16x8v vf = *(const bf16x8v*)&Vb[buf][d4 * 16 + l15]
                                           [((ks * 4 + q4) ^ swz) * 8];
          o[d4] = MFMA_BF16(pf[ks], vf, o[d4]);
        }
      }
#pragma unroll
      for (int ks = 0; ks < 2; ++ks) ol = MFMA_BF16(pf[ks], ones, ol);
      __builtin_amdgcn_s_setprio(0);
    }
  }

  // epilogue: y[b][t][h*64+d] = O / l  (fixed-max scale cancels)
  // PV output D-layout: q_row = rs + q4*4 + r, d = d4*16 + l15.
#pragma unroll
  for (int d4 = 0; d4 < 4; ++d4)
#pragma unroll
    for (int r = 0; r < 4; ++r) {
      int row = rs + q4 * 4 + r;
      y[((size_t)(bb * 4096 + row)) * 768 + hb * 64 + d4 * 16 + l15] =
          (bf16)(o[d4][r] / ol[r]);
    }
}

// ---------------------------------------------------------------------------
extern "C" void kernel_launch(void* const* d_in, const int* in_sizes, int n_in,
                              void* d_out, int out_size, void* d_ws,
                              size_t ws_size, hipStream_t stream) {
  const float* x = (const float*)d_in[0];       // (2,4096,768) f32
  const float* w_attn = (const float*)d_in[1];  // (768,2304) f32
  const float* b_attn = (const float*)d_in[2];  // (2304) f32
  const float* w_proj = (const float*)d_in[3];  // (768,768) f32
  const float* b_proj = (const float*)d_in[4];  // (768) f32
  float* out = (float*)d_out;                   // (8192*768) f32

  char* ws = (char*)d_ws;
  size_t off = 0;
  auto carve = [&](size_t elems) {
    char* p = ws + off;
    off += ((elems * sizeof(bf16) + 255) & ~(size_t)255);
    return (bf16*)p;
  };
  bf16* xb = carve((size_t)8192 * 768);      // x bf16; reused as vtb
  bf16* wt_attn = carve((size_t)2304 * 768);
  bf16* wt_proj = carve((size_t)768 * 768);
  bf16* qb = carve((size_t)24 * 4096 * 64);
  bf16* kb = carve((size_t)24 * 4096 * 64);
  bf16* vb = carve((size_t)24 * 4096 * 64);  // reused as yb
  bf16* vtb = xb;  // xb dead after QKV gemm
  bf16* yb = vb;   // vb dead after V transpose

  prep_kernel<<<5376, 256, 0, stream>>>(x, xb, w_attn, wt_attn, w_proj,
                                        wt_proj);
  gemm_kernel<1, 128><<<1152, 256, 0, stream>>>(xb, wt_attn, b_attn, 2304,
                                                nullptr, qb, kb, vb);
  transpose_bf16_kernel<<<dim3(64 / 32, 4096 / 32, 24), 256, 0, stream>>>(
      vb, vtb, 4096, 64);
  attn_kernel<<<dim3(768), 512, 0, stream>>>(qb, kb, vtb, yb);
  gemm_kernel<0, 64><<<768, 256, 0, stream>>>(yb, wt_proj, b_proj, 768, out,
                                              nullptr, nullptr, nullptr);
}

// Round 12
// 219.071 us; speedup vs baseline: 1.1025x; 1.1025x over previous
//
#include <hip/hip_runtime.h>

typedef __bf16 bf16;
typedef float f32x4 __attribute__((ext_vector_type(4)));
typedef bf16 bf16x8v __attribute__((ext_vector_type(8)));
typedef bf16 bf16x4v __attribute__((ext_vector_type(4)));

#define MFMA_BF16(a, b, c) __builtin_amdgcn_mfma_f32_16x16x32_bf16((a), (b), (c), 0, 0, 0)

// async global->LDS, 16B per lane (dest = wave-uniform base + lane*16)
__device__ __forceinline__ void async16(const bf16* g, bf16* l) {
  __builtin_amdgcn_global_load_lds(
      (const __attribute__((address_space(1))) void*)g,
      (__attribute__((address_space(3))) void*)l, 16, 0, 0);
}

// ---------------------------------------------------------------------------
// Fused prep: f32->bf16 convert of x  +  two transpose+convert of weights.
// ---------------------------------------------------------------------------
__global__ __launch_bounds__(256) void prep_kernel(
    const float* __restrict__ x, bf16* __restrict__ xb,
    const float* __restrict__ w_attn, bf16* __restrict__ wt_attn,
    const float* __restrict__ w_proj, bf16* __restrict__ wt_proj) {
  __shared__ float tile[32][33];
  const int b = blockIdx.x;
  if (b < 3072) {
    int i = b * 256 + threadIdx.x;
    const float4* p = (const float4*)x + (size_t)i * 2;
    float4 a = p[0], c = p[1];
    bf16x8v o;
    o[0] = (bf16)a.x; o[1] = (bf16)a.y; o[2] = (bf16)a.z; o[3] = (bf16)a.w;
    o[4] = (bf16)c.x; o[5] = (bf16)c.y; o[6] = (bf16)c.z; o[7] = (bf16)c.w;
    ((bf16x8v*)xb)[i] = o;
    return;
  }
  const float* in;
  bf16* out;
  int Ccols, bidx;
  if (b < 4800) {
    in = w_attn; out = wt_attn; Ccols = 2304; bidx = b - 3072;
  } else {
    in = w_proj; out = wt_proj; Ccols = 768; bidx = b - 4800;
  }
  const int R = 768;
  const int gx = Ccols / 32;
  const int c0 = (bidx % gx) * 32, r0 = (bidx / gx) * 32;
  const int tx = threadIdx.x & 31;
  const int ty = threadIdx.x >> 5;
#pragma unroll
  for (int i = 0; i < 4; ++i) {
    int r = ty + i * 8;
    tile[r][tx] = in[(size_t)(r0 + r) * Ccols + c0 + tx];
  }
  __syncthreads();
#pragma unroll
  for (int i = 0; i < 4; ++i) {
    int c = ty + i * 8;
    out[(size_t)(c0 + c) * R + r0 + tx] = (bf16)tile[tx][c];
  }
}

// ---------------------------------------------------------------------------
// Tiled bf16 transpose: out[z][c][r] = in[z][r][c].  R,C mult of 32.
// ---------------------------------------------------------------------------
__global__ __launch_bounds__(256) void transpose_bf16_kernel(
    const bf16* __restrict__ in, bf16* __restrict__ out, int R, int Ccols) {
  __shared__ bf16 tile[32][33];
  const bf16* inp = in + (size_t)blockIdx.z * R * Ccols;
  bf16* outp = out + (size_t)blockIdx.z * R * Ccols;
  int c0 = blockIdx.x * 32, r0 = blockIdx.y * 32;
  int tx = threadIdx.x & 31;
  int ty = threadIdx.x >> 5;
#pragma unroll
  for (int i = 0; i < 4; ++i) {
    int r = ty + i * 8;
    tile[r][tx] = inp[(size_t)(r0 + r) * Ccols + c0 + tx];
  }
  __syncthreads();
#pragma unroll
  for (int i = 0; i < 4; ++i) {
    int c = ty + i * 8;
    outp[(size_t)(c0 + c) * R + r0 + tx] = tile[tx][c];
  }
}

// ---------------------------------------------------------------------------
// GEMM: out[M][N] = A[M][768] * Bt[N][768]^T + bias[N]   (A,Bt bf16; bias f32)
// MODE 0: store FLOAT to outf.  MODE 1: scatter bf16 into q/k/v [b,h,t,d].
// BM x BN tile, BK=64, 4 waves (2m x 2n), async global_load_lds + XOR swizzle
// (conflict-free b128 frag reads).  XCD-affine 1-D grid (m contiguous/XCD).
//
// gemm<1>: 128x192 -> grid 768 = EXACTLY 3 blocks/CU (old 128x128 grid of
// 1152 = 4.5/CU: integer residency put 5 blocks on some CUs, ~11% overload
// tail) and 48 MFMA / 20 b128-reads per wave-K-iter (2.4:1 vs 2:1).
// gemm<0>: 64x128 -> 768 blocks = 3/CU (R11-measured small win).
// Requires: (8192/BM)%8==0, N%BN==0, block cols (BN) divide 768 segments.
// ---------------------------------------------------------------------------
template <int MODE, int BM, int BN>
__global__ __launch_bounds__(256, 3) void gemm_kernel(
    const bf16* __restrict__ A, const bf16* __restrict__ Bt,
    const float* __restrict__ bias, int N, float* __restrict__ outf,
    bf16* __restrict__ qo, bf16* __restrict__ ko, bf16* __restrict__ vo) {
  constexpr int Kdim = 768;
  constexpr int MI = BM / 32;  // per-wave m-fragments
  constexpr int NI = BN / 32;  // per-wave n-fragments
  constexpr int TPX = (8192 / BM) / 8;  // m-tiles per XCD
  __shared__ __align__(16) bf16 As[BM][64];
  __shared__ __align__(16) bf16 Bs[BN][64];
  const int tid = threadIdx.x;
  const int lane = tid & 63;
  const int wave = tid >> 6;
  const int wm = (wave >> 1) * (BM / 2), wn = (wave & 1) * (BN / 2);
  const int id = blockIdx.x;
  const int xcd = id & 7, j = id >> 3;
  const int m0 = (xcd * TPX + j % TPX) * BM;
  const int n0 = (j / TPX) * BN;
  const int l15 = lane & 15, q4 = lane >> 4;
  const int swz = l15 & 7;

  f32x4 acc[MI][NI] = {};

  const int gr = lane >> 3;        // row within 8-row group
  const int sj = (lane & 7) ^ gr;  // global source chunk (XOR swizzle)

  for (int k0 = 0; k0 < Kdim; k0 += 64) {
#pragma unroll
    for (int c = 0; c < BM / 32; ++c) {
      const int r0 = wave * (BM / 4) + c * 8;
      async16(A + (size_t)(m0 + r0 + gr) * Kdim + k0 + sj * 8, &As[r0][0]);
    }
#pragma unroll
    for (int c = 0; c < BN / 32; ++c) {
      const int r0 = wave * (BN / 4) + c * 8;
      async16(Bt + (size_t)(n0 + r0 + gr) * Kdim + k0 + sj * 8, &Bs[r0][0]);
    }
    __syncthreads();
#pragma unroll
    for (int ks = 0; ks < 2; ++ks) {
      bf16x8v af[MI], bfg[NI];
#pragma unroll
      for (int i = 0; i < MI; ++i)
        af[i] =
            *(const bf16x8v*)&As[wm + i * 16 + l15][((ks * 4 + q4) ^ swz) * 8];
#pragma unroll
      for (int i = 0; i < NI; ++i)
        bfg[i] =
            *(const bf16x8v*)&Bs[wn + i * 16 + l15][((ks * 4 + q4) ^ swz) * 8];
#pragma unroll
      for (int mi = 0; mi < MI; ++mi)
#pragma unroll
        for (int ni = 0; ni < NI; ++ni)
          acc[mi][ni] = MFMA_BF16(af[mi], bfg[ni], acc[mi][ni]);
    }
    __syncthreads();
  }

#pragma unroll
  for (int mi = 0; mi < MI; ++mi) {
#pragma unroll
    for (int ni = 0; ni < NI; ++ni) {
      int col = n0 + wn + ni * 16 + l15;
      float bv = bias[col];
#pragma unroll
      for (int r = 0; r < 4; ++r) {
        int row = m0 + wm + mi * 16 + q4 * 4 + r;
        float val = acc[mi][ni][r] + bv;
        if (MODE == 0) {
          outf[(size_t)row * N + col] = val;
        } else {
          int sel = col / 768;
          int cc = col - sel * 768;
          int h = cc >> 6, d = cc & 63;
          int b = row >> 12, t = row & 4095;
          bf16* dst = sel == 0 ? qo : (sel == 1 ? ko : vo);
          dst[((size_t)(b * 12 + h) * 4096 + t) * 64 + d] = (bf16)val;
        }
      }
    }
  }
}

// ---------------------------------------------------------------------------
// Flash attention — R9/R10 kernel VERBATIM (best measured: 85.6-86.4 us).
// Mirror-pair block {63-p, p}; 8 waves, one 16-row strip per wave.
// p MAP: bh=id%24, p=id/24 — proven best.  24 = 0 mod 8 -> per-bh XCD/L2
// affinity (FETCH 18.5MB).  R11's constant-SUM triplet remap kept affinity
// but grew within-CU spread (one long block + 2 short -> single-block tail,
// occupancy 53.5->50.4, +6us): the objective is min-MAX within the
// co-resident triplet, and the simple map is already near-optimal there.
// QK^T swapped (mfma(K,Q)); P via 4 ds_write_b64; swizzled b128 PV A-frag.
// 48 KB LDS, 3 blocks/CU, launch_bounds(512,6) = 24 waves/CU.
// ---------------------------------------------------------------------------
__global__ __launch_bounds__(512, 6) void attn_kernel(
    const bf16* __restrict__ q, const bf16* __restrict__ k,
    const bf16* __restrict__ vt, bf16* __restrict__ y) {
  __shared__ __align__(16) bf16 Kb[2][64][64];  // [key][d], swizzled
  __shared__ __align__(16) bf16 Vb[2][64][64];  // [d][key], swizzled
  __shared__ __align__(16) bf16 Ps[8][16][64];  // per-wave P, swizzled
  const int tid = threadIdx.x;
  const int lane = tid & 63, wave = tid >> 6;  // wave 0..7
  const int l15 = lane & 15, q4 = lane >> 4;
  const int swz = l15 & 7;
  const int id = blockIdx.x;
  const int bh = id % 24;
  const int p = id / 24;  // 0..31
  // wave role: one 16-row strip.  waves 0-3: big tile 63-p; 4-7: small tile p
  const int rs = (wave < 4) ? ((63 - p) * 64 + wave * 16)
                            : (p * 64 + (wave - 4) * 16);
  const int hb = bh % 12, bb = bh / 12;

  // staging geometry: one async16 wave-call covers 8 rows x 8 chunks (1 KB);
  // each of 8 waves stages one 8-row group of K and of V.
  const int gr = lane >> 3;        // row within 8-row group
  const int sj = (lane & 7) ^ gr;  // global source chunk (XOR swizzle)
  const bf16* kgbase = k + (size_t)bh * 4096 * 64;
  const bf16* vgbase = vt + (size_t)bh * 64 * 4096;

  bf16x8v ones;
#pragma unroll
  for (int j = 0; j < 8; ++j) ones[j] = (bf16)1.0f;

  // Q fragments for this wave's strip, pre-scaled by log2(e)/sqrt(64)
  bf16x8v qf[2];
  {
    const bf16* qrow = q + ((size_t)bh * 4096 + rs + l15) * 64 + q4 * 8;
#pragma unroll
    for (int ks = 0; ks < 2; ++ks) {
      bf16x8v t8 = *(const bf16x8v*)(qrow + ks * 32);
#pragma unroll
      for (int j = 0; j < 8; ++j) t8[j] = (bf16)((float)t8[j] * 0.18033688f);
      qf[ks] = t8;
    }
  }

  f32x4 o[4] = {};
  f32x4 ol = {};

  auto stage = [&](int kt, int buf) {
    const int t0k = kt * 64;
    async16(kgbase + (size_t)(t0k + wave * 8 + gr) * 64 + sj * 8,
            &Kb[buf][wave * 8][0]);
    async16(vgbase + (size_t)(wave * 8 + gr) * 4096 + t0k + sj * 8,
            &Vb[buf][wave * 8][0]);
  };

  // p = exp2(s - 28.854); full (no mask) variant
  auto sm_full = [&](f32x4 (&s)[4]) {
#pragma unroll
    for (int ni = 0; ni < 4; ++ni)
#pragma unroll
      for (int r = 0; r < 4; ++r)
        s[ni][r] = __builtin_amdgcn_exp2f(s[ni][r] - 28.8539008f);
  };
  // masked variant: local key (ni*16+q4*4+r) valid iff <= lim
  auto sm_mask = [&](f32x4 (&s)[4], int lim) {
#pragma unroll
    for (int ni = 0; ni < 4; ++ni)
#pragma unroll
      for (int r = 0; r < 4; ++r)
        s[ni][r] = (ni * 16 + q4 * 4 + r <= lim)
                       ? __builtin_amdgcn_exp2f(s[ni][r] - 28.8539008f)
                       : 0.0f;
  };
  // P row write: lane (q4,l15) owns keys ni*16 + q4*4 + {0..3} of q-row l15.
  auto pwrite = [&](const f32x4 (&s)[4]) {
#pragma unroll
    for (int ni = 0; ni < 4; ++ni) {
      bf16x4v pv4;
#pragma unroll
      for (int e = 0; e < 4; ++e) pv4[e] = (bf16)s[ni][e];
      const int jb = ni * 2 + (q4 >> 1);
      *(bf16x4v*)&Ps[wave][l15][((jb ^ (l15 & 7)) * 8) + (q4 & 1) * 4] = pv4;
    }
  };

  const int ktmax = 64 - p;  // tiles needed by the big tile
  stage(0, 0);

  for (int kt = 0; kt < ktmax; ++kt) {
    const int buf = kt & 1;
    __syncthreads();  // drains vmcnt: tile kt resident; buf^1 free
    if (kt + 1 < ktmax) stage(kt + 1, buf ^ 1);
    const int t0 = kt * 64;

    if (t0 <= rs + 15) {  // wave-uniform: this strip still has work
      // S^T = K Q^T (exp2 domain)
      // Lane (q4,l15): s[ni][r] = S[qrow = rs + l15][key = t0+ni*16+q4*4+r]
      f32x4 s[4] = {};
      __builtin_amdgcn_s_setprio(1);
#pragma unroll
      for (int ni = 0; ni < 4; ++ni) {
#pragma unroll
        for (int ks = 0; ks < 2; ++ks) {
          bf16x8v kf = *(const bf16x8v*)&Kb[buf][ni * 16 + l15]
                                           [((ks * 4 + q4) ^ swz) * 8];
          s[ni] = MFMA_BF16(kf, qf[ks], s[ni]);
        }
      }
      __builtin_amdgcn_s_setprio(0);

      // softmax + P write (masked only near the diagonal)
      if (t0 + 63 <= rs) sm_full(s); else sm_mask(s, rs + l15 - t0);
      pwrite(s);

      // PV A-frag: proven swizzled b128 read path (row = q_row = l15)
      bf16x8v pf[2];
#pragma unroll
      for (int ks = 0; ks < 2; ++ks)
        pf[ks] = *(const bf16x8v*)&Ps[wave][l15][((ks * 4 + q4) ^ swz) * 8];

      // O += P V ; rowsum l += P * ones
      __builtin_amdgcn_s_setprio(1);
#pragma unroll
      for (int d4 = 0; d4 < 4; ++d4) {
#pragma unroll
        for (int ks = 0; ks < 2; ++ks) {
          bf16x8v vf = *(const bf16x8v*)&Vb[buf][d4 * 16 + l15]
                                           [((ks * 4 + q4) ^ swz) * 8];
          o[d4] = MFMA_BF16(pf[ks], vf, o[d4]);
        }
      }
#pragma unroll
      for (int ks = 0; ks < 2; ++ks) ol = MFMA_BF16(pf[ks], ones, ol);
      __builtin_amdgcn_s_setprio(0);
    }
  }

  // epilogue: y[b][t][h*64+d] = O / l  (fixed-max scale cancels)
  // PV output D-layout: q_row = rs + q4*4 + r, d = d4*16 + l15.
#pragma unroll
  for (int d4 = 0; d4 < 4; ++d4)
#pragma unroll
    for (int r = 0; r < 4; ++r) {
      int row = rs + q4 * 4 + r;
      y[((size_t)(bb * 4096 + row)) * 768 + hb * 64 + d4 * 16 + l15] =
          (bf16)(o[d4][r] / ol[r]);
    }
}

// ---------------------------------------------------------------------------
extern "C" void kernel_launch(void* const* d_in, const int* in_sizes, int n_in,
                              void* d_out, int out_size, void* d_ws,
                              size_t ws_size, hipStream_t stream) {
  const float* x = (const float*)d_in[0];       // (2,4096,768) f32
  const float* w_attn = (const float*)d_in[1];  // (768,2304) f32
  const float* b_attn = (const float*)d_in[2];  // (2304) f32
  const float* w_proj = (const float*)d_in[3];  // (768,768) f32
  const float* b_proj = (const float*)d_in[4];  // (768) f32
  float* out = (float*)d_out;                   // (8192*768) f32

  char* ws = (char*)d_ws;
  size_t off = 0;
  auto carve = [&](size_t elems) {
    char* p = ws + off;
    off += ((elems * sizeof(bf16) + 255) & ~(size_t)255);
    return (bf16*)p;
  };
  bf16* xb = carve((size_t)8192 * 768);      // x bf16; reused as vtb
  bf16* wt_attn = carve((size_t)2304 * 768);
  bf16* wt_proj = carve((size_t)768 * 768);
  bf16* qb = carve((size_t)24 * 4096 * 64);
  bf16* kb = carve((size_t)24 * 4096 * 64);
  bf16* vb = carve((size_t)24 * 4096 * 64);  // reused as yb
  bf16* vtb = xb;  // xb dead after QKV gemm
  bf16* yb = vb;   // vb dead after V transpose

  prep_kernel<<<5376, 256, 0, stream>>>(x, xb, w_attn, wt_attn, w_proj,
                                        wt_proj);
  gemm_kernel<1, 128, 192><<<768, 256, 0, stream>>>(xb, wt_attn, b_attn, 2304,
                                                    nullptr, qb, kb, vb);
  transpose_bf16_kernel<<<dim3(64 / 32, 4096 / 32, 24), 256, 0, stream>>>(
      vb, vtb, 4096, 64);
  attn_kernel<<<dim3(768), 512, 0, stream>>>(qb, kb, vtb, yb);
  gemm_kernel<0, 64, 128><<<768, 256, 0, stream>>>(yb, wt_proj, b_proj, 768,
                                                   out, nullptr, nullptr,
                                                   nullptr);
}

// Round 13
// 213.124 us; speedup vs baseline: 1.1332x; 1.0279x over previous
//
#include <hip/hip_runtime.h>

typedef __bf16 bf16;
typedef float f32x4 __attribute__((ext_vector_type(4)));
typedef bf16 bf16x8v __attribute__((ext_vector_type(8)));
typedef bf16 bf16x4v __attribute__((ext_vector_type(4)));

#define MFMA_BF16(a, b, c) __builtin_amdgcn_mfma_f32_16x16x32_bf16((a), (b), (c), 0, 0, 0)

// async global->LDS, 16B per lane (dest = wave-uniform base + lane*16)
__device__ __forceinline__ void async16(const bf16* g, bf16* l) {
  __builtin_amdgcn_global_load_lds(
      (const __attribute__((address_space(1))) void*)g,
      (__attribute__((address_space(3))) void*)l, 16, 0, 0);
}

// ---------------------------------------------------------------------------
// Fused prep: f32->bf16 convert of x  +  two transpose+convert of weights.
// ---------------------------------------------------------------------------
__global__ __launch_bounds__(256) void prep_kernel(
    const float* __restrict__ x, bf16* __restrict__ xb,
    const float* __restrict__ w_attn, bf16* __restrict__ wt_attn,
    const float* __restrict__ w_proj, bf16* __restrict__ wt_proj) {
  __shared__ float tile[32][33];
  const int b = blockIdx.x;
  if (b < 3072) {
    int i = b * 256 + threadIdx.x;
    const float4* p = (const float4*)x + (size_t)i * 2;
    float4 a = p[0], c = p[1];
    bf16x8v o;
    o[0] = (bf16)a.x; o[1] = (bf16)a.y; o[2] = (bf16)a.z; o[3] = (bf16)a.w;
    o[4] = (bf16)c.x; o[5] = (bf16)c.y; o[6] = (bf16)c.z; o[7] = (bf16)c.w;
    ((bf16x8v*)xb)[i] = o;
    return;
  }
  const float* in;
  bf16* out;
  int Ccols, bidx;
  if (b < 4800) {
    in = w_attn; out = wt_attn; Ccols = 2304; bidx = b - 3072;
  } else {
    in = w_proj; out = wt_proj; Ccols = 768; bidx = b - 4800;
  }
  const int R = 768;
  const int gx = Ccols / 32;
  const int c0 = (bidx % gx) * 32, r0 = (bidx / gx) * 32;
  const int tx = threadIdx.x & 31;
  const int ty = threadIdx.x >> 5;
#pragma unroll
  for (int i = 0; i < 4; ++i) {
    int r = ty + i * 8;
    tile[r][tx] = in[(size_t)(r0 + r) * Ccols + c0 + tx];
  }
  __syncthreads();
#pragma unroll
  for (int i = 0; i < 4; ++i) {
    int c = ty + i * 8;
    out[(size_t)(c0 + c) * R + r0 + tx] = (bf16)tile[tx][c];
  }
}

// ---------------------------------------------------------------------------
// GEMM: out[M][N] = A[M][768] * Bt[N][768]^T + bias[N]   (A,Bt bf16; bias f32)
// MODE 0: store FLOAT to outf.  MODE 1: scatter bf16 into q/k [b,h,t,d] AND
// write V blocks (n0 >= 1536, block-uniform since 192 | 768) DIRECTLY
// TRANSPOSED to vo = vt[bh][d][t] via an in-LDS transpose — this replaces
// the standalone 25MB scalar-access transpose kernel entirely.
//
// In-LDS V transpose: after the K-loop the 48KB LDS is dead.  Phase 1 writes
// acc to vt_lds[d][t ^ ((d&15)<<3)] (XOR is 8-aligned; write banks
// (2q4)^(4*(l15&7)) -> 32 banks x2 = conflict-free); phase 2 reads b128
// (8 contiguous t per read, 16 lanes = one 256B row = 2/bank) and stores
// coalesced bf16x8 runs to vt[d][m0+t..].
//
// BM x BN tile, BK=64, 4 waves (2m x 2n), async global_load_lds + XOR swizzle
// (conflict-free b128 frag reads).  XCD-affine 1-D grid (m contiguous/XCD).
// gemm<1>: 128x192 -> grid 768 = exactly 3 blocks/CU (R12: +16us vs 4.5/CU).
// gemm<0>: 64x128 -> 768 blocks = 3/CU.
// ---------------------------------------------------------------------------
template <int MODE, int BM, int BN>
__global__ __launch_bounds__(256, 3) void gemm_kernel(
    const bf16* __restrict__ A, const bf16* __restrict__ Bt,
    const float* __restrict__ bias, int N, float* __restrict__ outf,
    bf16* __restrict__ qo, bf16* __restrict__ ko, bf16* __restrict__ vo) {
  constexpr int Kdim = 768;
  constexpr int MI = BM / 32;           // per-wave m-fragments
  constexpr int NI = BN / 32;           // per-wave n-fragments
  constexpr int TPX = (8192 / BM) / 8;  // m-tiles per XCD
  constexpr int BASE_E = (BM + BN) * 64;
  constexpr int VT_E = 192 * 128;
  constexpr int LDSE = (MODE == 1 && VT_E > BASE_E) ? VT_E : BASE_E;
  __shared__ __align__(16) bf16 lds_all[LDSE];
  bf16* asP = lds_all;
  bf16* bsP = lds_all + BM * 64;
  const int tid = threadIdx.x;
  const int lane = tid & 63;
  const int wave = tid >> 6;
  const int wm = (wave >> 1) * (BM / 2), wn = (wave & 1) * (BN / 2);
  const int id = blockIdx.x;
  const int xcd = id & 7, j = id >> 3;
  const int m0 = (xcd * TPX + j % TPX) * BM;
  const int n0 = (j / TPX) * BN;
  const int l15 = lane & 15, q4 = lane >> 4;
  const int swz = l15 & 7;

  f32x4 acc[MI][NI] = {};

  const int gr = lane >> 3;        // row within 8-row group
  const int sj = (lane & 7) ^ gr;  // global source chunk (XOR swizzle)

  for (int k0 = 0; k0 < Kdim; k0 += 64) {
#pragma unroll
    for (int c = 0; c < BM / 32; ++c) {
      const int r0 = wave * (BM / 4) + c * 8;
      async16(A + (size_t)(m0 + r0 + gr) * Kdim + k0 + sj * 8, asP + r0 * 64);
    }
#pragma unroll
    for (int c = 0; c < BN / 32; ++c) {
      const int r0 = wave * (BN / 4) + c * 8;
      async16(Bt + (size_t)(n0 + r0 + gr) * Kdim + k0 + sj * 8, bsP + r0 * 64);
    }
    __syncthreads();
#pragma unroll
    for (int ks = 0; ks < 2; ++ks) {
      bf16x8v af[MI], bfg[NI];
#pragma unroll
      for (int i = 0; i < MI; ++i)
        af[i] = *(const bf16x8v*)(asP + (wm + i * 16 + l15) * 64 +
                                  ((ks * 4 + q4) ^ swz) * 8);
#pragma unroll
      for (int i = 0; i < NI; ++i)
        bfg[i] = *(const bf16x8v*)(bsP + (wn + i * 16 + l15) * 64 +
                                   ((ks * 4 + q4) ^ swz) * 8);
#pragma unroll
      for (int mi = 0; mi < MI; ++mi)
#pragma unroll
        for (int ni = 0; ni < NI; ++ni)
          acc[mi][ni] = MFMA_BF16(af[mi], bfg[ni], acc[mi][ni]);
    }
    __syncthreads();
  }

  if constexpr (MODE == 1) {
    if (n0 >= 1536) {
      // -------- V block: in-LDS transpose, coalesced write to vt[d][t] ----
      bf16* vt = lds_all;  // [192][128], swizzled
#pragma unroll
      for (int mi = 0; mi < MI; ++mi) {
#pragma unroll
        for (int ni = 0; ni < NI; ++ni) {
          const int dl = wn + ni * 16 + l15;
          const float bv = bias[n0 + dl];
#pragma unroll
          for (int r = 0; r < 4; ++r) {
            const int tl = wm + mi * 16 + q4 * 4 + r;
            vt[dl * 128 + (tl ^ ((dl & 15) << 3))] =
                (bf16)(acc[mi][ni][r] + bv);
          }
        }
      }
      __syncthreads();
      const int bb_ = m0 >> 12;
      const int tblk = m0 & 4095;
#pragma unroll
      for (int i = 0; i < 12; ++i) {
        const int lin = i * 256 + tid;  // 0..3071 (192 d-rows x 16 chunks)
        const int dl = lin >> 4;
        const int p0 = (lin & 15) * 8;
        const int tb = p0 ^ ((dl & 15) << 3);  // 8-aligned, contiguous t
        bf16x8v v8 = *(const bf16x8v*)(vt + dl * 128 + p0);
        const int cc = n0 + dl - 1536;
        const int h = cc >> 6, dd = cc & 63;
        *(bf16x8v*)&vo[(((size_t)(bb_ * 12 + h) * 64 + dd) * 4096) + tblk +
                       tb] = v8;
      }
      return;
    }
  }

#pragma unroll
  for (int mi = 0; mi < MI; ++mi) {
#pragma unroll
    for (int ni = 0; ni < NI; ++ni) {
      int col = n0 + wn + ni * 16 + l15;
      float bv = bias[col];
#pragma unroll
      for (int r = 0; r < 4; ++r) {
        int row = m0 + wm + mi * 16 + q4 * 4 + r;
        float val = acc[mi][ni][r] + bv;
        if (MODE == 0) {
          outf[(size_t)row * N + col] = val;
        } else {
          int sel = col / 768;  // 0 or 1 here (V handled above)
          int cc = col - sel * 768;
          int h = cc >> 6, d = cc & 63;
          int b = row >> 12, t = row & 4095;
          bf16* dst = sel == 0 ? qo : ko;
          dst[((size_t)(b * 12 + h) * 4096 + t) * 64 + d] = (bf16)val;
        }
      }
    }
  }
}

// ---------------------------------------------------------------------------
// Flash attention — R12 kernel VERBATIM (best measured: 84.4-85.6 us).
// Mirror-pair block {63-p, p}; 8 waves, one 16-row strip per wave.
// p MAP: bh=id%24, p=id/24 — proven best (per-bh XCD/L2 affinity; R11's
// constant-sum remap regressed via within-CU max-spread).
// QK^T swapped (mfma(K,Q)); P via 4 ds_write_b64; swizzled b128 PV A-frag.
// 48 KB LDS, 3 blocks/CU, launch_bounds(512,6) = 24 waves/CU.
// ---------------------------------------------------------------------------
__global__ __launch_bounds__(512, 6) void attn_kernel(
    const bf16* __restrict__ q, const bf16* __restrict__ k,
    const bf16* __restrict__ vt, bf16* __restrict__ y) {
  __shared__ __align__(16) bf16 Kb[2][64][64];  // [key][d], swizzled
  __shared__ __align__(16) bf16 Vb[2][64][64];  // [d][key], swizzled
  __shared__ __align__(16) bf16 Ps[8][16][64];  // per-wave P, swizzled
  const int tid = threadIdx.x;
  const int lane = tid & 63, wave = tid >> 6;  // wave 0..7
  const int l15 = lane & 15, q4 = lane >> 4;
  const int swz = l15 & 7;
  const int id = blockIdx.x;
  const int bh = id % 24;
  const int p = id / 24;  // 0..31
  // wave role: one 16-row strip.  waves 0-3: big tile 63-p; 4-7: small tile p
  const int rs = (wave < 4) ? ((63 - p) * 64 + wave * 16)
                            : (p * 64 + (wave - 4) * 16);
  const int hb = bh % 12, bb = bh / 12;

  // staging geometry: one async16 wave-call covers 8 rows x 8 chunks (1 KB);
  // each of 8 waves stages one 8-row group of K and of V.
  const int gr = lane >> 3;        // row within 8-row group
  const int sj = (lane & 7) ^ gr;  // global source chunk (XOR swizzle)
  const bf16* kgbase = k + (size_t)bh * 4096 * 64;
  const bf16* vgbase = vt + (size_t)bh * 64 * 4096;

  bf16x8v ones;
#pragma unroll
  for (int j = 0; j < 8; ++j) ones[j] = (bf16)1.0f;

  // Q fragments for this wave's strip, pre-scaled by log2(e)/sqrt(64)
  bf16x8v qf[2];
  {
    const bf16* qrow = q + ((size_t)bh * 4096 + rs + l15) * 64 + q4 * 8;
#pragma unroll
    for (int ks = 0; ks < 2; ++ks) {
      bf16x8v t8 = *(const bf16x8v*)(qrow + ks * 32);
#pragma unroll
      for (int j = 0; j < 8; ++j) t8[j] = (bf16)((float)t8[j] * 0.18033688f);
      qf[ks] = t8;
    }
  }

  f32x4 o[4] = {};
  f32x4 ol = {};

  auto stage = [&](int kt, int buf) {
    const int t0k = kt * 64;
    async16(kgbase + (size_t)(t0k + wave * 8 + gr) * 64 + sj * 8,
            &Kb[buf][wave * 8][0]);
    async16(vgbase + (size_t)(wave * 8 + gr) * 4096 + t0k + sj * 8,
            &Vb[buf][wave * 8][0]);
  };

  // p = exp2(s - 28.854); full (no mask) variant
  auto sm_full = [&](f32x4 (&s)[4]) {
#pragma unroll
    for (int ni = 0; ni < 4; ++ni)
#pragma unroll
      for (int r = 0; r < 4; ++r)
        s[ni][r] = __builtin_amdgcn_exp2f(s[ni][r] - 28.8539008f);
  };
  // masked variant: local key (ni*16+q4*4+r) valid iff <= lim
  auto sm_mask = [&](f32x4 (&s)[4], int lim) {
#pragma unroll
    for (int ni = 0; ni < 4; ++ni)
#pragma unroll
      for (int r = 0; r < 4; ++r)
        s[ni][r] = (ni * 16 + q4 * 4 + r <= lim)
                       ? __builtin_amdgcn_exp2f(s[ni][r] - 28.8539008f)
                       : 0.0f;
  };
  // P row write: lane (q4,l15) owns keys ni*16 + q4*4 + {0..3} of q-row l15.
  auto pwrite = [&](const f32x4 (&s)[4]) {
#pragma unroll
    for (int ni = 0; ni < 4; ++ni) {
      bf16x4v pv4;
#pragma unroll
      for (int e = 0; e < 4; ++e) pv4[e] = (bf16)s[ni][e];
      const int jb = ni * 2 + (q4 >> 1);
      *(bf16x4v*)&Ps[wave][l15][((jb ^ (l15 & 7)) * 8) + (q4 & 1) * 4] = pv4;
    }
  };

  const int ktmax = 64 - p;  // tiles needed by the big tile
  stage(0, 0);

  for (int kt = 0; kt < ktmax; ++kt) {
    const int buf = kt & 1;
    __syncthreads();  // drains vmcnt: tile kt resident; buf^1 free
    if (kt + 1 < ktmax) stage(kt + 1, buf ^ 1);
    const int t0 = kt * 64;

    if (t0 <= rs + 15) {  // wave-uniform: this strip still has work
      // S^T = K Q^T (exp2 domain)
      // Lane (q4,l15): s[ni][r] = S[qrow = rs + l15][key = t0+ni*16+q4*4+r]
      f32x4 s[4] = {};
      __builtin_amdgcn_s_setprio(1);
#pragma unroll
      for (int ni = 0; ni < 4; ++ni) {
#pragma unroll
        for (int ks = 0; ks < 2; ++ks) {
          bf16x8v kf = *(const bf16x8v*)&Kb[buf][ni * 16 + l15]
                                           [((ks * 4 + q4) ^ swz) * 8];
          s[ni] = MFMA_BF16(kf, qf[ks], s[ni]);
        }
      }
      __builtin_amdgcn_s_setprio(0);

      // softmax + P write (masked only near the diagonal)
      if (t0 + 63 <= rs) sm_full(s); else sm_mask(s, rs + l15 - t0);
      pwrite(s);

      // PV A-frag: proven swizzled b128 read path (row = q_row = l15)
      bf16x8v pf[2];
#pragma unroll
      for (int ks = 0; ks < 2; ++ks)
        pf[ks] = *(const bf16x8v*)&Ps[wave][l15][((ks * 4 + q4) ^ swz) * 8];

      // O += P V ; rowsum l += P * ones
      __builtin_amdgcn_s_setprio(1);
#pragma unroll
      for (int d4 = 0; d4 < 4; ++d4) {
#pragma unroll
        for (int ks = 0; ks < 2; ++ks) {
          bf16x8v vf = *(const bf16x8v*)&Vb[buf][d4 * 16 + l15]
                                           [((ks * 4 + q4) ^ swz) * 8];
          o[d4] = MFMA_BF16(pf[ks], vf, o[d4]);
        }
      }
#pragma unroll
      for (int ks = 0; ks < 2; ++ks) ol = MFMA_BF16(pf[ks], ones, ol);
      __builtin_amdgcn_s_setprio(0);
    }
  }

  // epilogue: y[b][t][h*64+d] = O / l  (fixed-max scale cancels)
  // PV output D-layout: q_row = rs + q4*4 + r, d = d4*16 + l15.
#pragma unroll
  for (int d4 = 0; d4 < 4; ++d4)
#pragma unroll
    for (int r = 0; r < 4; ++r) {
      int row = rs + q4 * 4 + r;
      y[((size_t)(bb * 4096 + row)) * 768 + hb * 64 + d4 * 16 + l15] =
          (bf16)(o[d4][r] / ol[r]);
    }
}

// ---------------------------------------------------------------------------
extern "C" void kernel_launch(void* const* d_in, const int* in_sizes, int n_in,
                              void* d_out, int out_size, void* d_ws,
                              size_t ws_size, hipStream_t stream) {
  const float* x = (const float*)d_in[0];       // (2,4096,768) f32
  const float* w_attn = (const float*)d_in[1];  // (768,2304) f32
  const float* b_attn = (const float*)d_in[2];  // (2304) f32
  const float* w_proj = (const float*)d_in[3];  // (768,768) f32
  const float* b_proj = (const float*)d_in[4];  // (768) f32
  float* out = (float*)d_out;                   // (8192*768) f32

  char* ws = (char*)d_ws;
  size_t off = 0;
  auto carve = [&](size_t elems) {
    char* p = ws + off;
    off += ((elems * sizeof(bf16) + 255) & ~(size_t)255);
    return (bf16*)p;
  };
  bf16* xb = carve((size_t)8192 * 768);
  bf16* wt_attn = carve((size_t)2304 * 768);
  bf16* wt_proj = carve((size_t)768 * 768);
  bf16* qb = carve((size_t)24 * 4096 * 64);
  bf16* kb = carve((size_t)24 * 4096 * 64);
  bf16* vb = carve((size_t)24 * 4096 * 64);  // yb (attn output)
  // V^T scratch lives in d_out (25MB f32, only written by final gemm<0>;
  // gemm<1> writes vtb -> attn reads vtb -> gemm<0> overwrites with out).
  bf16* vtb = (bf16*)out;
  bf16* yb = vb;

  prep_kernel<<<5376, 256, 0, stream>>>(x, xb, w_attn, wt_attn, w_proj,
                                        wt_proj);
  gemm_kernel<1, 128, 192><<<768, 256, 0, stream>>>(xb, wt_attn, b_attn, 2304,
                                                    nullptr, qb, kb, vtb);
  attn_kernel<<<dim3(768), 512, 0, stream>>>(qb, kb, vtb, yb);
  gemm_kernel<0, 64, 128><<<768, 256, 0, stream>>>(yb, wt_proj, b_proj, 768,
                                                   out, nullptr, nullptr,
                                                   nullptr);
}